// Round 1
// baseline (1210.674 us; speedup 1.0000x reference)
//
#include <hip/hip_runtime.h>
#include <math.h>

#define B_ 2
#define T_ 2048
#define C_ 1024
#define H_ 16
#define HKV_ 4
#define G_ 4
#define HD_ 64
#define KVC_ 256   // HKV*HD

// ---------------- fp32 tiled GEMM: C[M,N] = A[M,K] @ B[K,N] ----------------
// 64x64 tile, 256 threads, 4x4 micro-tile per thread, K-tile 16.
__global__ __launch_bounds__(256) void gemm_f32(
    const float* __restrict__ A, const float* __restrict__ Bw,
    float* __restrict__ Cc, int M, int N, int K)
{
    __shared__ float As[16][68];   // [kk][row], pad 68 (272B stride, 16B-aligned cols)
    __shared__ float Bs[16][64];   // [kk][col]
    const int tx = threadIdx.x & 15, ty = threadIdx.x >> 4;
    const int row0 = blockIdx.y * 64, col0 = blockIdx.x * 64;
    float acc[4][4] = {};
    for (int kt = 0; kt < K; kt += 16) {
        #pragma unroll
        for (int i = 0; i < 4; i++) {
            int e = threadIdx.x + 256 * i;       // 0..1023
            int r = e >> 4, kk = e & 15;
            As[kk][r] = A[(size_t)(row0 + r) * K + kt + kk];
        }
        #pragma unroll
        for (int i = 0; i < 4; i++) {
            int e = threadIdx.x + 256 * i;
            int kk = e >> 6, c = e & 63;
            Bs[kk][c] = Bw[(size_t)(kt + kk) * N + col0 + c];
        }
        __syncthreads();
        #pragma unroll
        for (int kk = 0; kk < 16; kk++) {
            float a[4], b[4];
            #pragma unroll
            for (int i = 0; i < 4; i++) a[i] = As[kk][ty * 4 + i];
            #pragma unroll
            for (int j = 0; j < 4; j++) b[j] = Bs[kk][tx * 4 + j];
            #pragma unroll
            for (int i = 0; i < 4; i++)
                #pragma unroll
                for (int j = 0; j < 4; j++)
                    acc[i][j] += a[i] * b[j];
        }
        __syncthreads();
    }
    #pragma unroll
    for (int i = 0; i < 4; i++)
        #pragma unroll
        for (int j = 0; j < 4; j++)
            Cc[(size_t)(row0 + ty * 4 + i) * N + col0 + tx * 4 + j] = acc[i][j];
}

// ---------------- flash attention (fp32, online softmax, ALiBi + causal) ----
// grid: (T/64 q-tiles, B*H). block: 256 threads (16x16), 4x4 outputs/thread.
// Q layout [B*T, C] col = h*HD+d ; K/V layout [B*T, KVC] col = kh*HD+d.
// Y layout [B*T, C] col = h*HD+d  (== [B,T,H,HD] flattened, ready for @Wo).
__global__ __launch_bounds__(256) void attn_f32(
    const float* __restrict__ Q, const float* __restrict__ K,
    const float* __restrict__ V, float* __restrict__ Y)
{
    const int qt = blockIdx.x;
    const int bh = blockIdx.y;
    const int b  = bh >> 4;          // / H_
    const int h  = bh & 15;
    const int kh = h >> 2;           // / G_
    const float slope = exp2f(-0.5f * (float)(kh + 1));
    const float scale = 0.125f;      // 1/sqrt(64)

    __shared__ float Qs[64][68];     // [d][row]   (transposed)
    __shared__ float Ks[64][68];     // [d][key]   (transposed)
    __shared__ float Vs[64][68];     // [key][d]
    __shared__ float Ps[64][68];     // [key][row] (S then P, transposed)
    __shared__ float mrow[64], lrow[64], arow[64];

    const int tx = threadIdx.x & 15, ty = threadIdx.x >> 4;

    #pragma unroll
    for (int i = 0; i < 16; i++) {
        int e = threadIdx.x + 256 * i;          // 0..4095
        int r = e >> 6, d = e & 63;
        Qs[d][r] = Q[(size_t)(b * T_ + qt * 64 + r) * C_ + h * 64 + d];
    }
    if (threadIdx.x < 64) { mrow[threadIdx.x] = -1e30f; lrow[threadIdx.x] = 0.f; }
    float O[4][4] = {};
    __syncthreads();

    for (int jt = 0; jt <= qt; jt++) {
        // stage K (transposed) and V tiles
        #pragma unroll
        for (int i = 0; i < 16; i++) {
            int e = threadIdx.x + 256 * i;
            int j = e >> 6, d = e & 63;
            size_t g = (size_t)(b * T_ + jt * 64 + j) * KVC_ + kh * 64 + d;
            Ks[d][j] = K[g];
            Vs[j][d] = V[g];
        }
        __syncthreads();

        // S = Q K^T  (rows ty*4+a, keys tx*4+bb)
        float s[4][4] = {};
        #pragma unroll 4
        for (int d = 0; d < 64; d++) {
            float qv[4], kv[4];
            #pragma unroll
            for (int a = 0; a < 4; a++) qv[a] = Qs[d][ty * 4 + a];
            #pragma unroll
            for (int bb = 0; bb < 4; bb++) kv[bb] = Ks[d][tx * 4 + bb];
            #pragma unroll
            for (int a = 0; a < 4; a++)
                #pragma unroll
                for (int bb = 0; bb < 4; bb++)
                    s[a][bb] += qv[a] * kv[bb];
        }
        // scale + ALiBi + causal, write S transposed [key][row]
        #pragma unroll
        for (int a = 0; a < 4; a++) {
            int qr = qt * 64 + ty * 4 + a;
            #pragma unroll
            for (int bb = 0; bb < 4; bb++) {
                int kj = jt * 64 + tx * 4 + bb;
                float val = (kj <= qr) ? (s[a][bb] * scale + slope * (float)(kj - qr))
                                       : -1e30f;
                Ps[tx * 4 + bb][ty * 4 + a] = val;
            }
        }
        __syncthreads();

        // online softmax: one thread per row
        if (threadIdx.x < 64) {
            int r = threadIdx.x;
            float m_old = mrow[r];
            float m = m_old;
            #pragma unroll 8
            for (int j = 0; j < 64; j++) m = fmaxf(m, Ps[j][r]);
            float alpha = __expf(m_old - m);
            float lsum = 0.f;
            #pragma unroll 8
            for (int j = 0; j < 64; j++) {
                float p = __expf(Ps[j][r] - m);
                Ps[j][r] = p;
                lsum += p;
            }
            mrow[r] = m;
            lrow[r] = lrow[r] * alpha + lsum;
            arow[r] = alpha;
        }
        __syncthreads();

        // O = O*alpha + P @ V   (rows ty*4+a, dims tx*4+bb)
        #pragma unroll
        for (int a = 0; a < 4; a++) {
            float al = arow[ty * 4 + a];
            #pragma unroll
            for (int bb = 0; bb < 4; bb++) O[a][bb] *= al;
        }
        #pragma unroll 4
        for (int j = 0; j < 64; j++) {
            float p[4], vv[4];
            #pragma unroll
            for (int a = 0; a < 4; a++) p[a] = Ps[j][ty * 4 + a];
            #pragma unroll
            for (int bb = 0; bb < 4; bb++) vv[bb] = Vs[j][tx * 4 + bb];
            #pragma unroll
            for (int a = 0; a < 4; a++)
                #pragma unroll
                for (int bb = 0; bb < 4; bb++)
                    O[a][bb] += p[a] * vv[bb];
        }
        __syncthreads();
    }

    // epilogue: normalize and store
    #pragma unroll
    for (int a = 0; a < 4; a++) {
        int r = ty * 4 + a;
        float inv = 1.f / lrow[r];
        #pragma unroll
        for (int bb = 0; bb < 4; bb++) {
            Y[(size_t)(b * T_ + qt * 64 + r) * C_ + h * 64 + tx * 4 + bb] =
                O[a][bb] * inv;
        }
    }
}

extern "C" void kernel_launch(void* const* d_in, const int* in_sizes, int n_in,
                              void* d_out, int out_size, void* d_ws, size_t ws_size,
                              hipStream_t stream) {
    const float* x  = (const float*)d_in[0];
    const float* Wq = (const float*)d_in[1];
    const float* Wk = (const float*)d_in[2];
    const float* Wv = (const float*)d_in[3];
    const float* Wo = (const float*)d_in[4];
    float* out = (float*)d_out;

    float* Qws = (float*)d_ws;                       // [4096,1024]
    float* Kws = Qws + (size_t)B_ * T_ * C_;         // [4096,256]
    float* Vws = Kws + (size_t)B_ * T_ * KVC_;       // [4096,256]
    float* Yws = Vws + (size_t)B_ * T_ * KVC_;       // [4096,1024]

    const int M = B_ * T_;
    dim3 blk(256);
    gemm_f32<<<dim3(C_ / 64,   M / 64), blk, 0, stream>>>(x,   Wq, Qws, M, C_,   C_);
    gemm_f32<<<dim3(KVC_ / 64, M / 64), blk, 0, stream>>>(x,   Wk, Kws, M, KVC_, C_);
    gemm_f32<<<dim3(KVC_ / 64, M / 64), blk, 0, stream>>>(x,   Wv, Vws, M, KVC_, C_);
    attn_f32<<<dim3(T_ / 64, B_ * H_), blk, 0, stream>>>(Qws, Kws, Vws, Yws);
    gemm_f32<<<dim3(C_ / 64,   M / 64), blk, 0, stream>>>(Yws, Wo, out, M, C_,   C_);
}

// Round 2
// 611.200 us; speedup vs baseline: 1.9808x; 1.9808x over previous
//
#include <hip/hip_runtime.h>
#include <hip/hip_bf16.h>
#include <math.h>

#define B_ 2
#define T_ 2048
#define C_ 1024
#define H_ 16
#define HKV_ 4
#define G_ 4
#define HD_ 64
#define KVC_ 256   // HKV*HD

typedef __attribute__((ext_vector_type(8))) short bf16x8;
typedef __attribute__((ext_vector_type(4))) float f32x4;

static __device__ inline short f2bf(float f) {
    __hip_bfloat16 h = __float2bfloat16(f);
    short s;
    __builtin_memcpy(&s, &h, 2);
    return s;
}

// ---------------- fp32 tiled GEMM: C[M,N] = A[M,K] @ B[K,N] ----------------
// 64x64 tile, 256 threads, 4x4 micro-tile per thread, K-tile 16.
__global__ __launch_bounds__(256) void gemm_f32(
    const float* __restrict__ A, const float* __restrict__ Bw,
    float* __restrict__ Cc, int M, int N, int K)
{
    __shared__ float As[16][68];
    __shared__ float Bs[16][64];
    const int tx = threadIdx.x & 15, ty = threadIdx.x >> 4;
    const int row0 = blockIdx.y * 64, col0 = blockIdx.x * 64;
    float acc[4][4] = {};
    for (int kt = 0; kt < K; kt += 16) {
        #pragma unroll
        for (int i = 0; i < 4; i++) {
            int e = threadIdx.x + 256 * i;
            int r = e >> 4, kk = e & 15;
            As[kk][r] = A[(size_t)(row0 + r) * K + kt + kk];
        }
        #pragma unroll
        for (int i = 0; i < 4; i++) {
            int e = threadIdx.x + 256 * i;
            int kk = e >> 6, c = e & 63;
            Bs[kk][c] = Bw[(size_t)(kt + kk) * N + col0 + c];
        }
        __syncthreads();
        #pragma unroll
        for (int kk = 0; kk < 16; kk++) {
            float a[4], b[4];
            #pragma unroll
            for (int i = 0; i < 4; i++) a[i] = As[kk][ty * 4 + i];
            #pragma unroll
            for (int j = 0; j < 4; j++) b[j] = Bs[kk][tx * 4 + j];
            #pragma unroll
            for (int i = 0; i < 4; i++)
                #pragma unroll
                for (int j = 0; j < 4; j++)
                    acc[i][j] += a[i] * b[j];
        }
        __syncthreads();
    }
    #pragma unroll
    for (int i = 0; i < 4; i++)
        #pragma unroll
        for (int j = 0; j < 4; j++)
            Cc[(size_t)(row0 + ty * 4 + i) * N + col0 + tx * 4 + j] = acc[i][j];
}

// ---------------- MFMA flash attention (bf16 inputs, fp32 acc) -------------
// grid: (T/64, B*H). block 256 = 4 waves; wave w owns Q-rows w*16..w*16+15.
// mfma_f32_16x16x32_bf16:  A[m=lane&15][k=quad*8+j], B[k=quad*8+j][n=lane&15],
//                          C/D: col=lane&15, row=quad*4+reg.
#define LSTR 72   // LDS row stride in shorts (144 B: 16B-aligned, <=2-way conflicts)

__global__ __launch_bounds__(256) void attn_mfma(
    const float* __restrict__ Q, const float* __restrict__ K,
    const float* __restrict__ V, float* __restrict__ Y)
{
    const int qt = blockIdx.x, bh = blockIdx.y;
    const int b = bh >> 4, h = bh & 15, kh = h >> 2;
    const float slope = exp2f(-0.5f * (float)(kh + 1));
    const int tid = threadIdx.x;
    const int wave = tid >> 6, lane = tid & 63;
    const int l15 = lane & 15, quad = lane >> 4;

    __shared__ short Ks[64 * LSTR];  // [key][d]
    __shared__ short Vt[64 * LSTR];  // [d][key]
    __shared__ short Ps[64 * LSTR];  // [row][key] (wave-private row ranges)

    // Q fragments in registers, softmax scale (1/8) folded into the cast.
    bf16x8 qf[2];
    {
        const int qrow = qt * 64 + wave * 16 + l15;
        const float* qp = Q + (size_t)(b * T_ + qrow) * C_ + h * 64 + quad * 8;
        #pragma unroll
        for (int k0 = 0; k0 < 2; k0++)
            #pragma unroll
            for (int j = 0; j < 8; j++)
                qf[k0][j] = f2bf(qp[k0 * 32 + j] * 0.125f);
    }

    float m_r[4], l_r[4];
    f32x4 Oacc[4];   // [nt]: dim = nt*16+l15, row = quad*4+reg
    #pragma unroll
    for (int r = 0; r < 4; r++) { m_r[r] = -1e30f; l_r[r] = 0.f; }
    #pragma unroll
    for (int nt = 0; nt < 4; nt++) Oacc[nt] = (f32x4){0.f, 0.f, 0.f, 0.f};

    for (int jt = 0; jt <= qt; jt++) {
        __syncthreads();   // protect Ks/Vt from previous iteration's readers
        {
            const int key0 = tid >> 4;          // 0..15
            const int d4 = (tid & 15) * 4;
            #pragma unroll
            for (int kk = 0; kk < 4; kk++) {
                const int key = key0 + kk * 16;
                const size_t g = (size_t)(b * T_ + jt * 64 + key) * KVC_ + kh * 64 + d4;
                const float4 kv = *(const float4*)(K + g);
                const float4 vv = *(const float4*)(V + g);
                short* kd = &Ks[key * LSTR + d4];
                kd[0] = f2bf(kv.x); kd[1] = f2bf(kv.y);
                kd[2] = f2bf(kv.z); kd[3] = f2bf(kv.w);
                Vt[(d4 + 0) * LSTR + key] = f2bf(vv.x);
                Vt[(d4 + 1) * LSTR + key] = f2bf(vv.y);
                Vt[(d4 + 2) * LSTR + key] = f2bf(vv.z);
                Vt[(d4 + 3) * LSTR + key] = f2bf(vv.w);
            }
        }
        __syncthreads();

        // S = (Q*scale) K^T : rows quad*4+reg, keys nt*16+l15
        f32x4 s[4];
        #pragma unroll
        for (int nt = 0; nt < 4; nt++) {
            f32x4 acc = {0.f, 0.f, 0.f, 0.f};
            #pragma unroll
            for (int k0 = 0; k0 < 2; k0++) {
                bf16x8 kf = *(const bf16x8*)&Ks[(nt * 16 + l15) * LSTR + k0 * 32 + quad * 8];
                acc = __builtin_amdgcn_mfma_f32_16x16x32_bf16(qf[k0], kf, acc, 0, 0, 0);
            }
            s[nt] = acc;
        }

        // ALiBi + causal mask + row max
        const int qrow_base = qt * 64 + wave * 16 + quad * 4;
        const bool diag = (jt == qt);
        float mnew[4];
        #pragma unroll
        for (int r = 0; r < 4; r++) mnew[r] = m_r[r];
        #pragma unroll
        for (int nt = 0; nt < 4; nt++) {
            const int kcol = jt * 64 + nt * 16 + l15;
            #pragma unroll
            for (int r = 0; r < 4; r++) {
                const int qrow = qrow_base + r;
                float v = s[nt][r] + slope * (float)(kcol - qrow);
                if (diag && kcol > qrow) v = -1e30f;
                s[nt][r] = v;
                mnew[r] = fmaxf(mnew[r], v);
            }
        }
        #pragma unroll
        for (int r = 0; r < 4; r++) {
            float m = mnew[r];
            m = fmaxf(m, __shfl_xor(m, 1, 64));
            m = fmaxf(m, __shfl_xor(m, 2, 64));
            m = fmaxf(m, __shfl_xor(m, 4, 64));
            m = fmaxf(m, __shfl_xor(m, 8, 64));
            mnew[r] = m;
        }
        float alpha[4], psum[4];
        #pragma unroll
        for (int r = 0; r < 4; r++) {
            alpha[r] = __expf(m_r[r] - mnew[r]);
            m_r[r] = mnew[r];
            psum[r] = 0.f;
        }
        // P = exp(s - m) -> wave-private LDS rows (C-layout -> A-layout xform)
        #pragma unroll
        for (int nt = 0; nt < 4; nt++) {
            #pragma unroll
            for (int r = 0; r < 4; r++) {
                float p = __expf(s[nt][r] - m_r[r]);
                psum[r] += p;
                Ps[(wave * 16 + quad * 4 + r) * LSTR + nt * 16 + l15] = f2bf(p);
            }
        }
        #pragma unroll
        for (int r = 0; r < 4; r++) {
            float ps = psum[r];
            ps += __shfl_xor(ps, 1, 64);
            ps += __shfl_xor(ps, 2, 64);
            ps += __shfl_xor(ps, 4, 64);
            ps += __shfl_xor(ps, 8, 64);
            l_r[r] = l_r[r] * alpha[r] + ps;
        }
        // O = O*alpha + P @ V
        #pragma unroll
        for (int nt = 0; nt < 4; nt++)
            #pragma unroll
            for (int r = 0; r < 4; r++)
                Oacc[nt][r] *= alpha[r];

        bf16x8 pf[2];
        #pragma unroll
        for (int k0 = 0; k0 < 2; k0++)
            pf[k0] = *(const bf16x8*)&Ps[(wave * 16 + l15) * LSTR + k0 * 32 + quad * 8];
        #pragma unroll
        for (int nt = 0; nt < 4; nt++) {
            #pragma unroll
            for (int k0 = 0; k0 < 2; k0++) {
                bf16x8 vf = *(const bf16x8*)&Vt[(nt * 16 + l15) * LSTR + k0 * 32 + quad * 8];
                Oacc[nt] = __builtin_amdgcn_mfma_f32_16x16x32_bf16(pf[k0], vf, Oacc[nt], 0, 0, 0);
            }
        }
    }

    // epilogue: normalize, store Y[B*T, C] at col h*64+dim
    #pragma unroll
    for (int r = 0; r < 4; r++) {
        const float inv = 1.f / l_r[r];
        const int row = qt * 64 + wave * 16 + quad * 4 + r;
        float* yp = Y + (size_t)(b * T_ + row) * C_ + h * 64 + l15;
        #pragma unroll
        for (int nt = 0; nt < 4; nt++)
            yp[nt * 16] = Oacc[nt][r] * inv;
    }
}

extern "C" void kernel_launch(void* const* d_in, const int* in_sizes, int n_in,
                              void* d_out, int out_size, void* d_ws, size_t ws_size,
                              hipStream_t stream) {
    const float* x  = (const float*)d_in[0];
    const float* Wq = (const float*)d_in[1];
    const float* Wk = (const float*)d_in[2];
    const float* Wv = (const float*)d_in[3];
    const float* Wo = (const float*)d_in[4];
    float* out = (float*)d_out;

    float* Qws = (float*)d_ws;                       // [4096,1024]
    float* Kws = Qws + (size_t)B_ * T_ * C_;         // [4096,256]
    float* Vws = Kws + (size_t)B_ * T_ * KVC_;       // [4096,256]
    float* Yws = Vws + (size_t)B_ * T_ * KVC_;       // [4096,1024]

    const int M = B_ * T_;
    dim3 blk(256);
    gemm_f32<<<dim3(C_ / 64,   M / 64), blk, 0, stream>>>(x,   Wq, Qws, M, C_,   C_);
    gemm_f32<<<dim3(KVC_ / 64, M / 64), blk, 0, stream>>>(x,   Wk, Kws, M, KVC_, C_);
    gemm_f32<<<dim3(KVC_ / 64, M / 64), blk, 0, stream>>>(x,   Wv, Vws, M, KVC_, C_);
    attn_mfma<<<dim3(T_ / 64, B_ * H_), blk, 0, stream>>>(Qws, Kws, Vws, Yws);
    gemm_f32<<<dim3(C_ / 64,   M / 64), blk, 0, stream>>>(Yws, Wo, out, M, C_,   C_);
}

// Round 3
// 278.432 us; speedup vs baseline: 4.3482x; 2.1951x over previous
//
#include <hip/hip_runtime.h>
#include <hip/hip_bf16.h>
#include <math.h>

#define B_ 2
#define T_ 2048
#define C_ 1024
#define H_ 16
#define HKV_ 4
#define G_ 4
#define HD_ 64
#define KVC_ 256      // HKV*HD
#define NQKV_ 1536    // C_ + 2*KVC_

typedef __attribute__((ext_vector_type(8))) short bf16x8;
typedef __attribute__((ext_vector_type(4))) float f32x4;

static __device__ inline short f2bf(float f) {
    __hip_bfloat16 h = __float2bfloat16(f);
    short s;
    __builtin_memcpy(&s, &h, 2);
    return s;
}
static __device__ inline float bf2f(short s) {
    unsigned int u = ((unsigned int)(unsigned short)s) << 16;
    float f;
    __builtin_memcpy(&f, &u, 4);
    return f;
}

// async global->LDS, 16B per lane; lds base must be wave-uniform.
static __device__ inline void gload_lds16(const short* g, short* lds) {
    __builtin_amdgcn_global_load_lds(
        (const __attribute__((address_space(1))) unsigned int*)g,
        (__attribute__((address_space(3))) unsigned int*)lds, 16, 0, 0);
}

// ---------------- elementwise fp32 -> bf16 cast (8 elems/thread) ----------
__global__ __launch_bounds__(256) void cast_bf16(
    const float* __restrict__ in, short* __restrict__ out, int n)
{
    const int i = (blockIdx.x * 256 + threadIdx.x) * 8;
    if (i >= n) return;
    const float4 a = *(const float4*)(in + i);
    const float4 b = *(const float4*)(in + i + 4);
    bf16x8 o;
    o[0] = f2bf(a.x); o[1] = f2bf(a.y); o[2] = f2bf(a.z); o[3] = f2bf(a.w);
    o[4] = f2bf(b.x); o[5] = f2bf(b.y); o[6] = f2bf(b.z); o[7] = f2bf(b.w);
    *(bf16x8*)(out + i) = o;
}

// ---------------- transpose + cast: in[K][N] fp32 -> out[N][K] bf16 -------
__global__ __launch_bounds__(256) void transpose_cast(
    const float* __restrict__ in, short* __restrict__ out, int K, int N)
{
    __shared__ float t[32][33];
    const int tx = threadIdx.x, ty = threadIdx.y;     // 32 x 8
    const int n0 = blockIdx.x * 32, k0 = blockIdx.y * 32;
    #pragma unroll
    for (int j = 0; j < 4; j++)
        t[ty + j * 8][tx] = in[(size_t)(k0 + ty + j * 8) * N + n0 + tx];
    __syncthreads();
    #pragma unroll
    for (int j = 0; j < 4; j++)
        out[(size_t)(n0 + ty + j * 8) * K + k0 + tx] = f2bf(t[tx][ty + j * 8]);
}

// ---------------- bf16 MFMA GEMM (m97 structure) --------------------------
// C[M,N] = A[M,K] @ B[K,N], with B supplied TRANSPOSED (Bt[N][K]).
// 128x128 tile, BK=32, 4 waves each computing 64x64 (4x4 MFMA 16x16x32).
template <bool OUT_BF16>
__global__ __launch_bounds__(256) void gemm_bf16(
    const short* __restrict__ A, const short* __restrict__ Bt,
    void* __restrict__ Cout, int M, int N, int K)
{
    __shared__ short As[128 * 32];   // [m][k], rows 64B (global_load_lds layout)
    __shared__ short Bs[128 * 32];   // [n][k]
    const int tid = threadIdx.x;
    const int wave = tid >> 6, lane = tid & 63;
    const int l15 = lane & 15, quad = lane >> 4;
    const int row0 = blockIdx.y * 128, col0 = blockIdx.x * 128;
    const int wrow = (wave >> 1) * 64, wcol = (wave & 1) * 64;

    f32x4 acc[4][4];
    #pragma unroll
    for (int i = 0; i < 4; i++)
        #pragma unroll
        for (int j = 0; j < 4; j++)
            acc[i][j] = (f32x4){0.f, 0.f, 0.f, 0.f};

    for (int kt = 0; kt < K; kt += 32) {
        __syncthreads();
        #pragma unroll
        for (int c2 = 0; c2 < 2; c2++) {
            const int c = wave * 2 + c2;                // chunk 0..7 (16 rows each)
            const int r = c * 16 + (lane >> 2);
            const int kof = (lane & 3) * 8;
            gload_lds16(A  + (size_t)(row0 + r) * K + kt + kof, &As[c * 512]);
            gload_lds16(Bt + (size_t)(col0 + r) * K + kt + kof, &Bs[c * 512]);
        }
        __syncthreads();

        bf16x8 af[4], bf[4];
        #pragma unroll
        for (int mt = 0; mt < 4; mt++)
            af[mt] = *(const bf16x8*)&As[(wrow + mt * 16 + l15) * 32 + quad * 8];
        #pragma unroll
        for (int nt = 0; nt < 4; nt++)
            bf[nt] = *(const bf16x8*)&Bs[(wcol + nt * 16 + l15) * 32 + quad * 8];
        #pragma unroll
        for (int mt = 0; mt < 4; mt++)
            #pragma unroll
            for (int nt = 0; nt < 4; nt++)
                acc[mt][nt] = __builtin_amdgcn_mfma_f32_16x16x32_bf16(
                    af[mt], bf[nt], acc[mt][nt], 0, 0, 0);
    }

    // epilogue: D col=l15, row=quad*4+r
    #pragma unroll
    for (int mt = 0; mt < 4; mt++) {
        #pragma unroll
        for (int r = 0; r < 4; r++) {
            const size_t row = row0 + wrow + mt * 16 + quad * 4 + r;
            #pragma unroll
            for (int nt = 0; nt < 4; nt++) {
                const size_t col = col0 + wcol + nt * 16 + l15;
                if (OUT_BF16)
                    ((short*)Cout)[row * N + col] = f2bf(acc[mt][nt][r]);
                else
                    ((float*)Cout)[row * N + col] = acc[mt][nt][r];
            }
        }
    }
}

// ---------------- MFMA flash attention (bf16 QKV in fused buffer) ---------
// QKV[B*T][1536]: Q at col h*64, K at 1024+kh*64, V at 1280+kh*64.
// grid: (T/64, B*H) with qt REVERSED (longest blocks dispatch first).
// Y bf16 [B*T][C] at col h*64.
#define LSTR 72

__global__ __launch_bounds__(256) void attn_mfma(
    const short* __restrict__ QKV, short* __restrict__ Y)
{
    const int qt = (int)gridDim.x - 1 - (int)blockIdx.x;   // longest first
    const int bh = blockIdx.y;
    const int b = bh >> 4, h = bh & 15, kh = h >> 2;
    const float slope = exp2f(-0.5f * (float)(kh + 1));
    const int tid = threadIdx.x;
    const int wave = tid >> 6, lane = tid & 63;
    const int l15 = lane & 15, quad = lane >> 4;

    __shared__ short Ks[64 * LSTR];  // [key][d]
    __shared__ short Vt[64 * LSTR];  // [d][key]
    __shared__ short Ps[64 * LSTR];  // [row][key] (wave-private row ranges)

    const short* Qp = QKV + h * 64;
    const short* Kp = QKV + C_ + kh * 64;
    const short* Vp = QKV + C_ + KVC_ + kh * 64;

    // Q fragments in registers, softmax scale (1/8) folded in (exact pow2).
    bf16x8 qf[2];
    {
        const int qrow = qt * 64 + wave * 16 + l15;
        const short* qp = Qp + (size_t)(b * T_ + qrow) * NQKV_;
        #pragma unroll
        for (int k0 = 0; k0 < 2; k0++) {
            bf16x8 raw = *(const bf16x8*)(qp + k0 * 32 + quad * 8);
            #pragma unroll
            for (int j = 0; j < 8; j++)
                qf[k0][j] = f2bf(bf2f(raw[j]) * 0.125f);
        }
    }

    float m_r[4], l_r[4];
    f32x4 Oacc[4];
    #pragma unroll
    for (int r = 0; r < 4; r++) { m_r[r] = -1e30f; l_r[r] = 0.f; }
    #pragma unroll
    for (int nt = 0; nt < 4; nt++) Oacc[nt] = (f32x4){0.f, 0.f, 0.f, 0.f};

    for (int jt = 0; jt <= qt; jt++) {
        __syncthreads();
        {
            const int key = tid >> 2;            // 0..63
            const int d16 = (tid & 3) * 16;      // 0,16,32,48
            const size_t rb = (size_t)(b * T_ + jt * 64 + key) * NQKV_;
            const bf16x8 k0 = *(const bf16x8*)(Kp + rb + d16);
            const bf16x8 k1 = *(const bf16x8*)(Kp + rb + d16 + 8);
            *(bf16x8*)&Ks[key * LSTR + d16]     = k0;
            *(bf16x8*)&Ks[key * LSTR + d16 + 8] = k1;
            const bf16x8 v0 = *(const bf16x8*)(Vp + rb + d16);
            const bf16x8 v1 = *(const bf16x8*)(Vp + rb + d16 + 8);
            #pragma unroll
            for (int j = 0; j < 8; j++) {
                Vt[(d16 + j) * LSTR + key]     = v0[j];
                Vt[(d16 + 8 + j) * LSTR + key] = v1[j];
            }
        }
        __syncthreads();

        // S = (Q*scale) K^T : rows quad*4+r, keys nt*16+l15
        f32x4 s[4];
        #pragma unroll
        for (int nt = 0; nt < 4; nt++) {
            f32x4 a = {0.f, 0.f, 0.f, 0.f};
            #pragma unroll
            for (int k0 = 0; k0 < 2; k0++) {
                bf16x8 kf = *(const bf16x8*)&Ks[(nt * 16 + l15) * LSTR + k0 * 32 + quad * 8];
                a = __builtin_amdgcn_mfma_f32_16x16x32_bf16(qf[k0], kf, a, 0, 0, 0);
            }
            s[nt] = a;
        }

        // ALiBi + causal + row max
        const int qrow_base = qt * 64 + wave * 16 + quad * 4;
        const bool diag = (jt == qt);
        float mnew[4];
        #pragma unroll
        for (int r = 0; r < 4; r++) mnew[r] = m_r[r];
        #pragma unroll
        for (int nt = 0; nt < 4; nt++) {
            const int kcol = jt * 64 + nt * 16 + l15;
            #pragma unroll
            for (int r = 0; r < 4; r++) {
                const int qrow = qrow_base + r;
                float v = s[nt][r] + slope * (float)(kcol - qrow);
                if (diag && kcol > qrow) v = -1e30f;
                s[nt][r] = v;
                mnew[r] = fmaxf(mnew[r], v);
            }
        }
        #pragma unroll
        for (int r = 0; r < 4; r++) {
            float m = mnew[r];
            m = fmaxf(m, __shfl_xor(m, 1, 64));
            m = fmaxf(m, __shfl_xor(m, 2, 64));
            m = fmaxf(m, __shfl_xor(m, 4, 64));
            m = fmaxf(m, __shfl_xor(m, 8, 64));
            mnew[r] = m;
        }
        float alpha[4], psum[4];
        #pragma unroll
        for (int r = 0; r < 4; r++) {
            alpha[r] = __expf(m_r[r] - mnew[r]);
            m_r[r] = mnew[r];
            psum[r] = 0.f;
        }
        #pragma unroll
        for (int nt = 0; nt < 4; nt++) {
            #pragma unroll
            for (int r = 0; r < 4; r++) {
                float p = __expf(s[nt][r] - m_r[r]);
                psum[r] += p;
                Ps[(wave * 16 + quad * 4 + r) * LSTR + nt * 16 + l15] = f2bf(p);
            }
        }
        #pragma unroll
        for (int r = 0; r < 4; r++) {
            float ps = psum[r];
            ps += __shfl_xor(ps, 1, 64);
            ps += __shfl_xor(ps, 2, 64);
            ps += __shfl_xor(ps, 4, 64);
            ps += __shfl_xor(ps, 8, 64);
            l_r[r] = l_r[r] * alpha[r] + ps;
        }
        #pragma unroll
        for (int nt = 0; nt < 4; nt++)
            #pragma unroll
            for (int r = 0; r < 4; r++)
                Oacc[nt][r] *= alpha[r];

        bf16x8 pf[2];
        #pragma unroll
        for (int k0 = 0; k0 < 2; k0++)
            pf[k0] = *(const bf16x8*)&Ps[(wave * 16 + l15) * LSTR + k0 * 32 + quad * 8];
        #pragma unroll
        for (int nt = 0; nt < 4; nt++) {
            #pragma unroll
            for (int k0 = 0; k0 < 2; k0++) {
                bf16x8 vf = *(const bf16x8*)&Vt[(nt * 16 + l15) * LSTR + k0 * 32 + quad * 8];
                Oacc[nt] = __builtin_amdgcn_mfma_f32_16x16x32_bf16(pf[k0], vf, Oacc[nt], 0, 0, 0);
            }
        }
    }

    #pragma unroll
    for (int r = 0; r < 4; r++) {
        const float inv = 1.f / l_r[r];
        const int row = qt * 64 + wave * 16 + quad * 4 + r;
        short* yp = Y + (size_t)(b * T_ + row) * C_ + h * 64 + l15;
        #pragma unroll
        for (int nt = 0; nt < 4; nt++)
            yp[nt * 16] = f2bf(Oacc[nt][r] * inv);
    }
}

extern "C" void kernel_launch(void* const* d_in, const int* in_sizes, int n_in,
                              void* d_out, int out_size, void* d_ws, size_t ws_size,
                              hipStream_t stream) {
    const float* x  = (const float*)d_in[0];
    const float* Wq = (const float*)d_in[1];
    const float* Wk = (const float*)d_in[2];
    const float* Wv = (const float*)d_in[3];
    const float* Wo = (const float*)d_in[4];
    float* out = (float*)d_out;

    const int M = B_ * T_;                           // 4096
    short* xb  = (short*)d_ws;                       // [4096][1024]
    short* Wt  = xb  + (size_t)M * C_;               // [1536][1024]  (QKV^T)
    short* Wot = Wt  + (size_t)NQKV_ * C_;           // [1024][1024]  (Wo^T)
    short* QKV = Wot + (size_t)C_ * C_;              // [4096][1536]
    short* Yb  = QKV + (size_t)M * NQKV_;            // [4096][1024]

    cast_bf16<<<dim3(M * C_ / (256 * 8)), dim3(256), 0, stream>>>(x, xb, M * C_);
    transpose_cast<<<dim3(32, 32), dim3(32, 8), 0, stream>>>(Wq, Wt,              C_, C_);
    transpose_cast<<<dim3(8, 32),  dim3(32, 8), 0, stream>>>(Wk, Wt + C_ * C_,    C_, KVC_);
    transpose_cast<<<dim3(8, 32),  dim3(32, 8), 0, stream>>>(Wv, Wt + (C_+KVC_)*C_, C_, KVC_);
    transpose_cast<<<dim3(32, 32), dim3(32, 8), 0, stream>>>(Wo, Wot,             C_, C_);

    gemm_bf16<true><<<dim3(NQKV_ / 128, M / 128), dim3(256), 0, stream>>>(
        xb, Wt, QKV, M, NQKV_, C_);
    attn_mfma<<<dim3(T_ / 64, B_ * H_), dim3(256), 0, stream>>>(QKV, Yb);
    gemm_bf16<false><<<dim3(C_ / 128, M / 128), dim3(256), 0, stream>>>(
        Yb, Wot, out, M, C_, C_);
}

// Round 4
// 240.086 us; speedup vs baseline: 5.0427x; 1.1597x over previous
//
#include <hip/hip_runtime.h>
#include <hip/hip_bf16.h>
#include <math.h>

#define B_ 2
#define T_ 2048
#define C_ 1024
#define H_ 16
#define HKV_ 4
#define G_ 4
#define HD_ 64
#define KVC_ 256      // HKV*HD
#define NQKV_ 1536    // C_ + 2*KVC_

typedef __attribute__((ext_vector_type(8))) short bf16x8;
typedef __attribute__((ext_vector_type(4))) float f32x4;

static __device__ inline short f2bf(float f) {
    __hip_bfloat16 h = __float2bfloat16(f);
    short s;
    __builtin_memcpy(&s, &h, 2);
    return s;
}
static __device__ inline float bf2f(short s) {
    unsigned int u = ((unsigned int)(unsigned short)s) << 16;
    float f;
    __builtin_memcpy(&f, &u, 4);
    return f;
}

// async global->LDS, 16B per lane; lds base must be wave-uniform.
static __device__ inline void gload_lds16(const short* g, short* lds) {
    __builtin_amdgcn_global_load_lds(
        (const __attribute__((address_space(1))) unsigned int*)g,
        (__attribute__((address_space(3))) unsigned int*)lds, 16, 0, 0);
}

// ---- DPP 16-lane butterfly reductions (VALU pipe, not LDS) ----------------
template <int CTRL>
static __device__ inline float dpp_mov(float x) {
    int xi = __builtin_bit_cast(int, x);
    int r = __builtin_amdgcn_update_dpp(0, xi, CTRL, 0xF, 0xF, true);
    return __builtin_bit_cast(float, r);
}
static __device__ inline float dpp_max16(float x) {
    x = fmaxf(x, dpp_mov<0xB1>(x));   // quad_perm(1,0,3,2)  xor1
    x = fmaxf(x, dpp_mov<0x4E>(x));   // quad_perm(2,3,0,1)  xor2
    x = fmaxf(x, dpp_mov<0x141>(x));  // row_half_mirror     combine quads in 8
    x = fmaxf(x, dpp_mov<0x140>(x));  // row_mirror          combine halves in 16
    return x;
}
static __device__ inline float dpp_sum16(float x) {
    x += dpp_mov<0xB1>(x);
    x += dpp_mov<0x4E>(x);
    x += dpp_mov<0x141>(x);
    x += dpp_mov<0x140>(x);
    return x;
}

// ---------------- elementwise fp32 -> bf16 cast (8 elems/thread) ----------
__global__ __launch_bounds__(256) void cast_bf16(
    const float* __restrict__ in, short* __restrict__ out, int n)
{
    const int i = (blockIdx.x * 256 + threadIdx.x) * 8;
    if (i >= n) return;
    const float4 a = *(const float4*)(in + i);
    const float4 b = *(const float4*)(in + i + 4);
    bf16x8 o;
    o[0] = f2bf(a.x); o[1] = f2bf(a.y); o[2] = f2bf(a.z); o[3] = f2bf(a.w);
    o[4] = f2bf(b.x); o[5] = f2bf(b.y); o[6] = f2bf(b.z); o[7] = f2bf(b.w);
    *(bf16x8*)(out + i) = o;
}

// ---------------- transpose + cast: in[K][N] fp32 -> out[N][K] bf16 -------
__global__ __launch_bounds__(256) void transpose_cast(
    const float* __restrict__ in, short* __restrict__ out, int K, int N)
{
    __shared__ float t[32][33];
    const int tx = threadIdx.x, ty = threadIdx.y;     // 32 x 8
    const int n0 = blockIdx.x * 32, k0 = blockIdx.y * 32;
    #pragma unroll
    for (int j = 0; j < 4; j++)
        t[ty + j * 8][tx] = in[(size_t)(k0 + ty + j * 8) * N + n0 + tx];
    __syncthreads();
    #pragma unroll
    for (int j = 0; j < 4; j++)
        out[(size_t)(n0 + ty + j * 8) * K + k0 + tx] = f2bf(t[tx][ty + j * 8]);
}

// ---------------- bf16 MFMA GEMM (m97 structure) --------------------------
template <bool OUT_BF16>
__global__ __launch_bounds__(256) void gemm_bf16(
    const short* __restrict__ A, const short* __restrict__ Bt,
    void* __restrict__ Cout, int M, int N, int K)
{
    __shared__ short As[128 * 32];
    __shared__ short Bs[128 * 32];
    const int tid = threadIdx.x;
    const int wave = tid >> 6, lane = tid & 63;
    const int l15 = lane & 15, quad = lane >> 4;
    const int row0 = blockIdx.y * 128, col0 = blockIdx.x * 128;
    const int wrow = (wave >> 1) * 64, wcol = (wave & 1) * 64;

    f32x4 acc[4][4];
    #pragma unroll
    for (int i = 0; i < 4; i++)
        #pragma unroll
        for (int j = 0; j < 4; j++)
            acc[i][j] = (f32x4){0.f, 0.f, 0.f, 0.f};

    for (int kt = 0; kt < K; kt += 32) {
        __syncthreads();
        #pragma unroll
        for (int c2 = 0; c2 < 2; c2++) {
            const int c = wave * 2 + c2;
            const int r = c * 16 + (lane >> 2);
            const int kof = (lane & 3) * 8;
            gload_lds16(A  + (size_t)(row0 + r) * K + kt + kof, &As[c * 512]);
            gload_lds16(Bt + (size_t)(col0 + r) * K + kt + kof, &Bs[c * 512]);
        }
        __syncthreads();

        bf16x8 af[4], bf[4];
        #pragma unroll
        for (int mt = 0; mt < 4; mt++)
            af[mt] = *(const bf16x8*)&As[(wrow + mt * 16 + l15) * 32 + quad * 8];
        #pragma unroll
        for (int nt = 0; nt < 4; nt++)
            bf[nt] = *(const bf16x8*)&Bs[(wcol + nt * 16 + l15) * 32 + quad * 8];
        #pragma unroll
        for (int mt = 0; mt < 4; mt++)
            #pragma unroll
            for (int nt = 0; nt < 4; nt++)
                acc[mt][nt] = __builtin_amdgcn_mfma_f32_16x16x32_bf16(
                    af[mt], bf[nt], acc[mt][nt], 0, 0, 0);
    }

    #pragma unroll
    for (int mt = 0; mt < 4; mt++) {
        #pragma unroll
        for (int r = 0; r < 4; r++) {
            const size_t row = row0 + wrow + mt * 16 + quad * 4 + r;
            #pragma unroll
            for (int nt = 0; nt < 4; nt++) {
                const size_t col = col0 + wcol + nt * 16 + l15;
                if (OUT_BF16)
                    ((short*)Cout)[row * N + col] = f2bf(acc[mt][nt][r]);
                else
                    ((float*)Cout)[row * N + col] = acc[mt][nt][r];
            }
        }
    }
}

// ---------------- K/V tiling prepass --------------------------------------
// QKV[B*T][1536] -> Kt[(b*4+kh)*32+jt][64key][64d], Vt[...][64d][64key]
// (8 KB contiguous tiles; attention stages them with pure b128 ops)
__global__ __launch_bounds__(256) void kv_tile(
    const short* __restrict__ QKV, short* __restrict__ Kt, short* __restrict__ Vt)
{
    __shared__ short Ls[64 * 72];
    const int jt = blockIdx.x;         // 0..31
    const int bk = blockIdx.y;         // 0..7 = b*4+kh
    const int b = bk >> 2, kh = bk & 3;
    const int tid = threadIdx.x;
    const int key = tid >> 2, d16 = (tid & 3) * 16;
    const size_t src = (size_t)(b * T_ + jt * 64 + key) * NQKV_ + C_ + kh * 64 + d16;
    const size_t tbase = (size_t)(bk * 32 + jt) * 4096;

    // K: straight tiled copy
    *(bf16x8*)(Kt + tbase + key * 64 + d16)     = *(const bf16x8*)(QKV + src);
    *(bf16x8*)(Kt + tbase + key * 64 + d16 + 8) = *(const bf16x8*)(QKV + src + 8);

    // V: transpose through LDS
    *(bf16x8*)&Ls[key * 72 + d16]     = *(const bf16x8*)(QKV + src + KVC_);
    *(bf16x8*)&Ls[key * 72 + d16 + 8] = *(const bf16x8*)(QKV + src + KVC_ + 8);
    __syncthreads();
    const int d = tid >> 2, k16 = (tid & 3) * 16;
    bf16x8 o0, o1;
    #pragma unroll
    for (int i = 0; i < 8; i++) o0[i] = Ls[(k16 + i) * 72 + d];
    #pragma unroll
    for (int i = 0; i < 8; i++) o1[i] = Ls[(k16 + 8 + i) * 72 + d];
    *(bf16x8*)(Vt + tbase + d * 64 + k16)     = o0;
    *(bf16x8*)(Vt + tbase + d * 64 + k16 + 8) = o1;
}

// ---------------- MFMA flash attention ------------------------------------
// grid: (T/64, B*H), qt reversed (longest first). 4 waves, 16 Q-rows each.
// K/V staged from pre-tiled global with b128-only LDS ops + reg prefetch.
#define LSTR 72

__global__ __launch_bounds__(256) void attn_mfma(
    const short* __restrict__ QKV, const short* __restrict__ Ktg,
    const short* __restrict__ Vtg, short* __restrict__ Y)
{
    const int qt = (int)gridDim.x - 1 - (int)blockIdx.x;
    const int bh = blockIdx.y;
    const int b = bh >> 4, h = bh & 15, kh = h >> 2;
    const float slope = exp2f(-0.5f * (float)(kh + 1));
    const int tid = threadIdx.x;
    const int wave = tid >> 6, lane = tid & 63;
    const int l15 = lane & 15, quad = lane >> 4;

    __shared__ short Ks[64 * LSTR];  // [key][d]
    __shared__ short Vs[64 * LSTR];  // [d][key]
    __shared__ short Ps[64 * LSTR];  // [row][key] (wave-private rows)

    const size_t tb0 = (size_t)((b * HKV_ + kh) * 32) * 4096;

    // staging offsets: elem e -> (row=e>>6, col=e&63); LDS row stride 72
    const int e0 = tid * 8, e1 = (256 + tid) * 8;
    const int r0 = e0 >> 6, c0 = e0 & 63;
    const int r1 = e1 >> 6, c1 = e1 & 63;

    // Q fragments (registers); softmax scale 1/8 folded in (exact pow2)
    bf16x8 qf[2];
    {
        const int qrow = qt * 64 + wave * 16 + l15;
        const short* qp = QKV + (size_t)(b * T_ + qrow) * NQKV_ + h * 64;
        #pragma unroll
        for (int k0 = 0; k0 < 2; k0++) {
            bf16x8 raw = *(const bf16x8*)(qp + k0 * 32 + quad * 8);
            #pragma unroll
            for (int j = 0; j < 8; j++)
                qf[k0][j] = f2bf(bf2f(raw[j]) * 0.125f);
        }
    }

    float m_r[4], l_r[4];
    f32x4 Oacc[4];
    #pragma unroll
    for (int r = 0; r < 4; r++) { m_r[r] = -1e30f; l_r[r] = 0.f; }
    #pragma unroll
    for (int nt = 0; nt < 4; nt++) Oacc[nt] = (f32x4){0.f, 0.f, 0.f, 0.f};

    // prefetch tile jt=0 into registers
    bf16x8 kr0, kr1, vr0, vr1;
    {
        const short* kt = Ktg + tb0;
        const short* vt = Vtg + tb0;
        kr0 = *(const bf16x8*)(kt + e0); kr1 = *(const bf16x8*)(kt + e1);
        vr0 = *(const bf16x8*)(vt + e0); vr1 = *(const bf16x8*)(vt + e1);
    }

    for (int jt = 0; jt <= qt; jt++) {
        __syncthreads();                       // LDS consumers of jt-1 done
        *(bf16x8*)&Ks[r0 * LSTR + c0] = kr0;
        *(bf16x8*)&Ks[r1 * LSTR + c1] = kr1;
        *(bf16x8*)&Vs[r0 * LSTR + c0] = vr0;
        *(bf16x8*)&Vs[r1 * LSTR + c1] = vr1;
        __syncthreads();                       // LDS ready
        if (jt < qt) {                         // prefetch jt+1 during compute
            const short* kt = Ktg + tb0 + (size_t)(jt + 1) * 4096;
            const short* vt = Vtg + tb0 + (size_t)(jt + 1) * 4096;
            kr0 = *(const bf16x8*)(kt + e0); kr1 = *(const bf16x8*)(kt + e1);
            vr0 = *(const bf16x8*)(vt + e0); vr1 = *(const bf16x8*)(vt + e1);
        }

        // S = (Q*scale) K^T : rows quad*4+r, keys nt*16+l15
        f32x4 s[4];
        #pragma unroll
        for (int nt = 0; nt < 4; nt++) {
            f32x4 a = {0.f, 0.f, 0.f, 0.f};
            #pragma unroll
            for (int k0 = 0; k0 < 2; k0++) {
                bf16x8 kf = *(const bf16x8*)&Ks[(nt * 16 + l15) * LSTR + k0 * 32 + quad * 8];
                a = __builtin_amdgcn_mfma_f32_16x16x32_bf16(qf[k0], kf, a, 0, 0, 0);
            }
            s[nt] = a;
        }

        // ALiBi + causal + row max (DPP reductions within 16-lane rows)
        const int qrow_base = qt * 64 + wave * 16 + quad * 4;
        const bool diag = (jt == qt);
        float mnew[4];
        #pragma unroll
        for (int r = 0; r < 4; r++) mnew[r] = m_r[r];
        #pragma unroll
        for (int nt = 0; nt < 4; nt++) {
            const int kcol = jt * 64 + nt * 16 + l15;
            #pragma unroll
            for (int r = 0; r < 4; r++) {
                const int qrow = qrow_base + r;
                float v = s[nt][r] + slope * (float)(kcol - qrow);
                if (diag && kcol > qrow) v = -1e30f;
                s[nt][r] = v;
                mnew[r] = fmaxf(mnew[r], v);
            }
        }
        #pragma unroll
        for (int r = 0; r < 4; r++) mnew[r] = dpp_max16(mnew[r]);

        float alpha[4], psum[4];
        #pragma unroll
        for (int r = 0; r < 4; r++) {
            alpha[r] = __expf(m_r[r] - mnew[r]);
            m_r[r] = mnew[r];
            psum[r] = 0.f;
        }
        #pragma unroll
        for (int nt = 0; nt < 4; nt++) {
            #pragma unroll
            for (int r = 0; r < 4; r++) {
                float p = __expf(s[nt][r] - m_r[r]);
                psum[r] += p;
                Ps[(wave * 16 + quad * 4 + r) * LSTR + nt * 16 + l15] = f2bf(p);
            }
        }
        #pragma unroll
        for (int r = 0; r < 4; r++)
            l_r[r] = l_r[r] * alpha[r] + dpp_sum16(psum[r]);

        #pragma unroll
        for (int nt = 0; nt < 4; nt++)
            #pragma unroll
            for (int r = 0; r < 4; r++)
                Oacc[nt][r] *= alpha[r];

        bf16x8 pf[2];
        #pragma unroll
        for (int k0 = 0; k0 < 2; k0++)
            pf[k0] = *(const bf16x8*)&Ps[(wave * 16 + l15) * LSTR + k0 * 32 + quad * 8];
        #pragma unroll
        for (int nt = 0; nt < 4; nt++) {
            #pragma unroll
            for (int k0 = 0; k0 < 2; k0++) {
                bf16x8 vf = *(const bf16x8*)&Vs[(nt * 16 + l15) * LSTR + k0 * 32 + quad * 8];
                Oacc[nt] = __builtin_amdgcn_mfma_f32_16x16x32_bf16(pf[k0], vf, Oacc[nt], 0, 0, 0);
            }
        }
    }

    #pragma unroll
    for (int r = 0; r < 4; r++) {
        const float inv = 1.f / l_r[r];
        const int row = qt * 64 + wave * 16 + quad * 4 + r;
        short* yp = Y + (size_t)(b * T_ + row) * C_ + h * 64 + l15;
        #pragma unroll
        for (int nt = 0; nt < 4; nt++)
            yp[nt * 16] = f2bf(Oacc[nt][r] * inv);
    }
}

extern "C" void kernel_launch(void* const* d_in, const int* in_sizes, int n_in,
                              void* d_out, int out_size, void* d_ws, size_t ws_size,
                              hipStream_t stream) {
    const float* x  = (const float*)d_in[0];
    const float* Wq = (const float*)d_in[1];
    const float* Wk = (const float*)d_in[2];
    const float* Wv = (const float*)d_in[3];
    const float* Wo = (const float*)d_in[4];
    float* out = (float*)d_out;

    const int M = B_ * T_;                           // 4096
    short* xb  = (short*)d_ws;                       // [4096][1024]
    short* Wt  = xb  + (size_t)M * C_;               // [1536][1024]
    short* Wot = Wt  + (size_t)NQKV_ * C_;           // [1024][1024]
    short* QKV = Wot + (size_t)C_ * C_;              // [4096][1536]
    short* Yb  = QKV + (size_t)M * NQKV_;            // [4096][1024]
    short* Ktg = Yb  + (size_t)M * C_;               // [8][32][4096]
    short* Vtg = Ktg + (size_t)8 * 32 * 4096;        // [8][32][4096]

    cast_bf16<<<dim3(M * C_ / (256 * 8)), dim3(256), 0, stream>>>(x, xb, M * C_);
    transpose_cast<<<dim3(32, 32), dim3(32, 8), 0, stream>>>(Wq, Wt,                C_, C_);
    transpose_cast<<<dim3(8, 32),  dim3(32, 8), 0, stream>>>(Wk, Wt + C_ * C_,      C_, KVC_);
    transpose_cast<<<dim3(8, 32),  dim3(32, 8), 0, stream>>>(Wv, Wt + (C_+KVC_)*C_, C_, KVC_);
    transpose_cast<<<dim3(32, 32), dim3(32, 8), 0, stream>>>(Wo, Wot,               C_, C_);

    gemm_bf16<true><<<dim3(NQKV_ / 128, M / 128), dim3(256), 0, stream>>>(
        xb, Wt, QKV, M, NQKV_, C_);
    kv_tile<<<dim3(32, 8), dim3(256), 0, stream>>>(QKV, Ktg, Vtg);
    attn_mfma<<<dim3(T_ / 64, B_ * H_), dim3(256), 0, stream>>>(QKV, Ktg, Vtg, Yb);
    gemm_bf16<false><<<dim3(C_ / 128, M / 128), dim3(256), 0, stream>>>(
        Yb, Wot, out, M, C_, C_);
}